// Round 1
// baseline (129.093 us; speedup 1.0000x reference)
//
#include <hip/hip_runtime.h>
#include <hip/hip_bf16.h>
#include <stdint.h>

// Problem constants: B=4, S=1024, D=1024, N=32, R=128; T = B*S = 4096.
// Pipeline:
//   xb  = bf16(x)                      (T x D)
//   FKT = bf16(fk) transposed          (N*R x D)   [FKT[nR+r][d] = fk[n][d][r]]
//   RKT = bf16(rk) transposed          (D x N*R)   [RKT[d][nR+r] = rk[n][r][d]]
//   ALLH = xb @ FKT^T                  (T x N*R)  bf16   GEMM1
//   HW[t][nR+r] = rw[t][n] * sum_n' fw[t][n']*ALLH[t][n'R+r]   (middle, in-place)
//   out  = HW @ RKT^T                  (T x D)    fp32   GEMM2

typedef __attribute__((ext_vector_type(8))) short bf16x8;
typedef __attribute__((ext_vector_type(4))) float f32x4;

#define GLOAD_LDS16(gp, lp) __builtin_amdgcn_global_load_lds( \
    (const __attribute__((address_space(1))) void*)(gp), \
    (__attribute__((address_space(3))) void*)(lp), 16, 0, 0)

__device__ __forceinline__ unsigned short f2bf(float f) {
  uint32_t u = __float_as_uint(f);
  u += 0x7FFFu + ((u >> 16) & 1u);   // round-to-nearest-even
  return (unsigned short)(u >> 16);
}
__device__ __forceinline__ float bf2f(unsigned short b) {
  return __uint_as_float(((uint32_t)b) << 16);
}

// ---------------- prep: cast x to bf16 (vectorized) ----------------
__global__ void cast_f32_bf16(const float4* __restrict__ in,
                              ushort4* __restrict__ out, int n4) {
  int i = blockIdx.x * blockDim.x + threadIdx.x;
  if (i < n4) {
    float4 v = in[i];
    ushort4 o;
    o.x = f2bf(v.x); o.y = f2bf(v.y); o.z = f2bf(v.z); o.w = f2bf(v.w);
    out[i] = o;
  }
}

// ---------------- prep: batched transpose + cast -------------------
// in: (BATCH, ROWS, COLS) fp32  ->  out: (BATCH, COLS, ROWS) bf16
// 64x64 tiles, 256 threads.
__global__ void transpose_cast(const float* __restrict__ in,
                               unsigned short* __restrict__ out,
                               int ROWS, int COLS, int tiles_per_batch, int ctiles) {
  __shared__ unsigned short tile[64][65];
  int bid = blockIdx.x;
  int b  = bid / tiles_per_batch;
  int tt = bid % tiles_per_batch;
  int rt = tt / ctiles, ct = tt % ctiles;
  const float* inb = in + (size_t)b * ROWS * COLS;
  unsigned short* outb = out + (size_t)b * ROWS * COLS;
  int lr = threadIdx.x >> 6;   // 0..3
  int lc = threadIdx.x & 63;   // 0..63
  int r0 = rt * 64, c0 = ct * 64;
#pragma unroll
  for (int i = 0; i < 16; ++i) {
    int r = lr * 16 + i;
    tile[r][lc] = f2bf(inb[(size_t)(r0 + r) * COLS + c0 + lc]);
  }
  __syncthreads();
#pragma unroll
  for (int i = 0; i < 16; ++i) {
    int c = lr * 16 + i;
    outb[(size_t)(c0 + c) * ROWS + r0 + lc] = tile[lc][c];
  }
}

// ---------------- middle: combine over experts + expand (in-place) --
// allh: (T, N*R) bf16, in-place becomes HW.
// h[t][r] = sum_n fw[t][n] * allh[t][n*128 + r]
// allh[t][n*128 + r] <- bf16(rw[t][n] * h[t][r])
__global__ void middle_kernel(unsigned short* __restrict__ allh,
                              const float* __restrict__ fw,
                              const float* __restrict__ rw) {
  int t = blockIdx.x;        // 0..4095
  int r = threadIdx.x;       // 0..127
  __shared__ float sfw[32], srw[32];
  if (threadIdx.x < 32)      sfw[threadIdx.x] = fw[t * 32 + threadIdx.x];
  else if (threadIdx.x < 64) srw[threadIdx.x - 32] = rw[t * 32 + threadIdx.x - 32];
  __syncthreads();
  size_t base = (size_t)t * 4096;
  float acc = 0.f;
#pragma unroll
  for (int n = 0; n < 32; ++n) acc += sfw[n] * bf2f(allh[base + n * 128 + r]);
#pragma unroll
  for (int n = 0; n < 32; ++n) allh[base + n * 128 + r] = f2bf(srw[n] * acc);
}

// ---------------- bf16 GEMM: C = A @ BT^T ---------------------------
// A: (M, K) bf16 row-major.  BT: (N, K) bf16 row-major (i.e. B col-major).
// C: (M, N), bf16 or fp32.  Tiles BM x BN, BK=64, 256 threads (2x2 waves).
// global_load_lds (16B) staging with pre-swizzled source; XOR-swizzled
// ds_read_b128 on the read side (T2 st-pattern, both-sides).
template <int BM, int BN, bool OUT_BF16>
__global__ __launch_bounds__(256, 2) void gemm_bt(
    const unsigned short* __restrict__ A,
    const unsigned short* __restrict__ BT,
    void* __restrict__ Cout, int M, int N, int K) {
  constexpr int BK = 64;
  constexpr int MREP = BM / 32;   // 16x16 frags per wave, M dir
  constexpr int NREP = BN / 32;   // 16x16 frags per wave, N dir
  __shared__ __align__(16) unsigned short As[BM * BK];
  __shared__ __align__(16) unsigned short Bs[BN * BK];

  const int tid = threadIdx.x;
  const int lane = tid & 63, wid = tid >> 6;
  const int wy = wid >> 1, wx = wid & 1;
  const int brow = blockIdx.y * BM;
  const int bcol = blockIdx.x * BN;

  f32x4 acc[MREP][NREP] = {};

  const int srow = tid >> 3;   // 0..31 (rows per staging inst = 32)
  const int sslot = tid & 7;   // 16B slot within 64-el row

  for (int k0 = 0; k0 < K; k0 += BK) {
    // ---- stage A (BM x 64) ----
#pragma unroll
    for (int i = 0; i < BM / 32; ++i) {
      int row = i * 32 + srow;
      int gslot = sslot ^ (row & 7);                 // inverse-swizzled SOURCE
      const unsigned short* g = A + (size_t)(brow + row) * K + k0 + gslot * 8;
      GLOAD_LDS16(g, &As[row * BK + sslot * 8]);     // linear DEST
    }
    // ---- stage B (BN x 64) ----
#pragma unroll
    for (int i = 0; i < BN / 32; ++i) {
      int row = i * 32 + srow;
      int gslot = sslot ^ (row & 7);
      const unsigned short* g = BT + (size_t)(bcol + row) * K + k0 + gslot * 8;
      GLOAD_LDS16(g, &Bs[row * BK + sslot * 8]);
    }
    __syncthreads();   // compiler emits vmcnt(0) drain here

#pragma unroll
    for (int ks = 0; ks < 2; ++ks) {               // two K=32 sub-steps
      const int kg = lane >> 4;                    // k-group 0..3
      const int slot = ks * 4 + kg;
      bf16x8 af[MREP], bfr[NREP];
#pragma unroll
      for (int m = 0; m < MREP; ++m) {
        int row = wy * (BM / 2) + m * 16 + (lane & 15);
        af[m] = *(const bf16x8*)&As[row * BK + ((slot ^ (row & 7)) * 8)];
      }
#pragma unroll
      for (int n = 0; n < NREP; ++n) {
        int row = wx * (BN / 2) + n * 16 + (lane & 15);
        bfr[n] = *(const bf16x8*)&Bs[row * BK + ((slot ^ (row & 7)) * 8)];
      }
#pragma unroll
      for (int m = 0; m < MREP; ++m)
#pragma unroll
        for (int n = 0; n < NREP; ++n)
          acc[m][n] = __builtin_amdgcn_mfma_f32_16x16x32_bf16(
              af[m], bfr[n], acc[m][n], 0, 0, 0);
    }
    __syncthreads();
  }

  // ---- epilogue: C/D layout col = lane&15, row = (lane>>4)*4 + j ----
  const int crow0 = brow + wy * (BM / 2);
  const int ccol0 = bcol + wx * (BN / 2);
#pragma unroll
  for (int m = 0; m < MREP; ++m) {
#pragma unroll
    for (int n = 0; n < NREP; ++n) {
      int r0 = crow0 + m * 16 + ((lane >> 4) * 4);
      int c = ccol0 + n * 16 + (lane & 15);
#pragma unroll
      for (int j = 0; j < 4; ++j) {
        if constexpr (OUT_BF16) {
          ((unsigned short*)Cout)[(size_t)(r0 + j) * N + c] = f2bf(acc[m][n][j]);
        } else {
          ((float*)Cout)[(size_t)(r0 + j) * N + c] = acc[m][n][j];
        }
      }
    }
  }
}

extern "C" void kernel_launch(void* const* d_in, const int* in_sizes, int n_in,
                              void* d_out, int out_size, void* d_ws, size_t ws_size,
                              hipStream_t stream) {
  const float* x  = (const float*)d_in[0];
  const float* fw = (const float*)d_in[1];
  const float* rw = (const float*)d_in[2];
  const float* fk = (const float*)d_in[3];
  const float* rk = (const float*)d_in[4];
  float* out = (float*)d_out;

  char* ws = (char*)d_ws;
  unsigned short* xb   = (unsigned short*)(ws);                     // 8 MB  (4096 x 1024)
  unsigned short* fkt  = (unsigned short*)(ws + (8u  << 20));       // 8 MB  (4096 x 1024)
  unsigned short* rkt  = (unsigned short*)(ws + (16u << 20));       // 8 MB  (1024 x 4096)
  unsigned short* allh = (unsigned short*)(ws + (24u << 20));       // 32 MB (4096 x 4096)

  // 1) cast x -> bf16
  cast_f32_bf16<<<4096, 256, 0, stream>>>((const float4*)x, (ushort4*)xb, 1048576);
  // 2) fk (32,1024,128) -> FKT (32,128,1024) == (4096 x 1024)
  transpose_cast<<<1024, 256, 0, stream>>>(fk, fkt, 1024, 128, 32, 2);
  // 3) rk (4096,1024) -> RKT (1024 x 4096)
  transpose_cast<<<1024, 256, 0, stream>>>(rk, rkt, 4096, 1024, 1024, 16);
  // 4) GEMM1: ALLH = xb @ FKT^T   (4096 x 4096, K=1024), bf16 out
  gemm_bt<128, 128, true><<<dim3(32, 32), 256, 0, stream>>>(xb, fkt, (void*)allh,
                                                            4096, 4096, 1024);
  // 5) middle: combine over n with fw, expand with rw (in place)
  middle_kernel<<<4096, 128, 0, stream>>>(allh, fw, rw);
  // 6) GEMM2: out = HW @ RKT^T    (4096 x 1024, K=4096), fp32 out
  gemm_bt<64, 128, false><<<dim3(8, 64), 256, 0, stream>>>(allh, rkt, (void*)out,
                                                           4096, 1024, 4096);
}

// Round 2
// 104.825 us; speedup vs baseline: 1.2315x; 1.2315x over previous
//
#include <hip/hip_runtime.h>
#include <hip/hip_bf16.h>
#include <stdint.h>

// B=4, S=1024, D=1024, N=32, R=128; T = B*S = 4096.
// Pipeline:
//   xb    = bf16(x)                       (T x D)
//   FKT   = bf16(fk) transposed           (N*R x D)
//   RKT   = bf16(rk) transposed           (D x N*R)
//   ALLHW[t, n*128+r] = fw[t,n] * (xb @ FKT^T)   bf16  (GEMM1, fw in epilogue)
//   h[t,r] = sum_n ALLHW[t, n*128+r]             bf16  (reduce)
//   out = sum_n diag(rw[:,n]) * (h @ rk[n])      f32   (gemm2_fused:
//         h-slice LDS-resident, A-frags hoisted, per-expert accn + rw fold)

typedef __attribute__((ext_vector_type(8))) short bf16x8;
typedef __attribute__((ext_vector_type(4))) float f32x4;

#define GLOAD_LDS16(gp, lp) __builtin_amdgcn_global_load_lds( \
    (const __attribute__((address_space(1))) void*)(gp), \
    (__attribute__((address_space(3))) void*)(lp), 16, 0, 0)

__device__ __forceinline__ unsigned short f2bf(float f) {
  uint32_t u = __float_as_uint(f);
  u += 0x7FFFu + ((u >> 16) & 1u);   // RNE
  return (unsigned short)(u >> 16);
}
__device__ __forceinline__ float bf2f(unsigned short b) {
  return __uint_as_float(((uint32_t)b) << 16);
}

// ---------------- prep: cast x to bf16 ----------------
__global__ void cast_f32_bf16(const float4* __restrict__ in,
                              ushort4* __restrict__ out, int n4) {
  int i = blockIdx.x * blockDim.x + threadIdx.x;
  if (i < n4) {
    float4 v = in[i];
    ushort4 o;
    o.x = f2bf(v.x); o.y = f2bf(v.y); o.z = f2bf(v.z); o.w = f2bf(v.w);
    out[i] = o;
  }
}

// ---------------- prep: batched transpose + cast -------------------
__global__ void transpose_cast(const float* __restrict__ in,
                               unsigned short* __restrict__ out,
                               int ROWS, int COLS, int tiles_per_batch, int ctiles) {
  __shared__ unsigned short tile[64][65];
  int bid = blockIdx.x;
  int b  = bid / tiles_per_batch;
  int tt = bid % tiles_per_batch;
  int rt = tt / ctiles, ct = tt % ctiles;
  const float* inb = in + (size_t)b * ROWS * COLS;
  unsigned short* outb = out + (size_t)b * ROWS * COLS;
  int lr = threadIdx.x >> 6;
  int lc = threadIdx.x & 63;
  int r0 = rt * 64, c0 = ct * 64;
#pragma unroll
  for (int i = 0; i < 16; ++i) {
    int r = lr * 16 + i;
    tile[r][lc] = f2bf(inb[(size_t)(r0 + r) * COLS + c0 + lc]);
  }
  __syncthreads();
#pragma unroll
  for (int i = 0; i < 16; ++i) {
    int c = lr * 16 + i;
    outb[(size_t)(c0 + c) * ROWS + r0 + lc] = tile[lc][c];
  }
}

// ---------------- reduce: h[t,r] = sum_n ALLHW[t, n*128+r] ----------
__global__ void reduce_h(const unsigned short* __restrict__ allhw,
                         unsigned short* __restrict__ h) {
  int tid = threadIdx.x;
  int t = blockIdx.x * 16 + (tid >> 4);
  int r8 = tid & 15;
  const unsigned short* p = allhw + (size_t)t * 4096 + r8 * 8;
  float acc[8] = {0,0,0,0,0,0,0,0};
#pragma unroll
  for (int n = 0; n < 32; ++n) {
    bf16x8 v = *(const bf16x8*)(p + n * 128);
#pragma unroll
    for (int j = 0; j < 8; ++j) acc[j] += bf2f((unsigned short)v[j]);
  }
  bf16x8 o;
#pragma unroll
  for (int j = 0; j < 8; ++j) o[j] = (short)f2bf(acc[j]);
  *(bf16x8*)(h + (size_t)t * 128 + r8 * 8) = o;
}

// ---------------- GEMM1: C = fw-weighted (A @ BT^T) -----------------
// A: (M,K) bf16 rm. BT: (N,K) bf16 rm. C: (M,N) bf16.
// BN=128 => each block column is exactly one expert n = blockIdx.x.
template <int BM, int BN>
__global__ __launch_bounds__(256, 2) void gemm_bt(
    const unsigned short* __restrict__ A,
    const unsigned short* __restrict__ BT,
    const float* __restrict__ fw,
    unsigned short* __restrict__ Cout, int M, int N, int K) {
  constexpr int BK = 64;
  constexpr int MREP = BM / 32;
  constexpr int NREP = BN / 32;
  __shared__ __align__(16) unsigned short As[BM * BK];
  __shared__ __align__(16) unsigned short Bs[BN * BK];

  const int tid = threadIdx.x;
  const int lane = tid & 63, wid = tid >> 6;
  const int wy = wid >> 1, wx = wid & 1;
  const int brow = blockIdx.y * BM;
  const int bcol = blockIdx.x * BN;
  const int nexp = blockIdx.x;              // expert id (BN==128==R)

  f32x4 acc[MREP][NREP] = {};

  const int srow = tid >> 3;
  const int sslot = tid & 7;

  for (int k0 = 0; k0 < K; k0 += BK) {
#pragma unroll
    for (int i = 0; i < BM / 32; ++i) {
      int row = i * 32 + srow;
      int gslot = sslot ^ (row & 7);
      GLOAD_LDS16(A + (size_t)(brow + row) * K + k0 + gslot * 8,
                  &As[row * BK + sslot * 8]);
    }
#pragma unroll
    for (int i = 0; i < BN / 32; ++i) {
      int row = i * 32 + srow;
      int gslot = sslot ^ (row & 7);
      GLOAD_LDS16(BT + (size_t)(bcol + row) * K + k0 + gslot * 8,
                  &Bs[row * BK + sslot * 8]);
    }
    __syncthreads();

#pragma unroll
    for (int ks = 0; ks < 2; ++ks) {
      const int kg = lane >> 4;
      const int slot = ks * 4 + kg;
      bf16x8 af[MREP], bfr[NREP];
#pragma unroll
      for (int m = 0; m < MREP; ++m) {
        int row = wy * (BM / 2) + m * 16 + (lane & 15);
        af[m] = *(const bf16x8*)&As[row * BK + ((slot ^ (row & 7)) * 8)];
      }
#pragma unroll
      for (int n = 0; n < NREP; ++n) {
        int row = wx * (BN / 2) + n * 16 + (lane & 15);
        bfr[n] = *(const bf16x8*)&Bs[row * BK + ((slot ^ (row & 7)) * 8)];
      }
#pragma unroll
      for (int m = 0; m < MREP; ++m)
#pragma unroll
        for (int n = 0; n < NREP; ++n)
          acc[m][n] = __builtin_amdgcn_mfma_f32_16x16x32_bf16(
              af[m], bfr[n], acc[m][n], 0, 0, 0);
    }
    __syncthreads();
  }

  const int crow0 = brow + wy * (BM / 2);
  const int ccol0 = bcol + wx * (BN / 2);
#pragma unroll
  for (int m = 0; m < MREP; ++m) {
    int r0 = crow0 + m * 16 + ((lane >> 4) * 4);
    float fwv[4];
#pragma unroll
    for (int j = 0; j < 4; ++j) fwv[j] = fw[(size_t)(r0 + j) * 32 + nexp];
#pragma unroll
    for (int n = 0; n < NREP; ++n) {
      int c = ccol0 + n * 16 + (lane & 15);
#pragma unroll
      for (int j = 0; j < 4; ++j)
        Cout[(size_t)(r0 + j) * N + c] = f2bf(fwv[j] * acc[m][n][j]);
    }
  }
}

// ---------------- GEMM2 fused: out = sum_n diag(rw_n)*(h @ rk[n]) ----
// h: (4096,128) bf16. rkt: (1024, 4096) bf16 [d][n*128+r]. rw: (4096,32) f32.
// out: (4096,1024) f32. BM=128 (t), BN=64 (d). grid (16, 32), 256 thr.
__global__ __launch_bounds__(256, 2) void gemm2_fused(
    const unsigned short* __restrict__ h,
    const unsigned short* __restrict__ rkt,
    const float* __restrict__ rw,
    float* __restrict__ out) {
  constexpr int BM = 128, BN = 64;
  __shared__ __align__(16) unsigned short h_lds[BM * 128];     // 32 KB
  __shared__ __align__(16) unsigned short Bs[BN * 128];        // 16 KB
  __shared__ __align__(16) unsigned short rw_lds[32 * BM];     // 8 KB (bf16)

  const int tid = threadIdx.x;
  const int lane = tid & 63, wid = tid >> 6;
  const int wy = wid >> 1, wx = wid & 1;
  const int brow = blockIdx.y * BM;   // token rows
  const int bcol = blockIdx.x * BN;   // d cols

  // ---- stage h block (once): 128 rows x 128 cols, swizzled source ----
  {
    int srow = tid >> 4, sslot = tid & 15;
#pragma unroll
    for (int i = 0; i < 8; ++i) {
      int row = i * 16 + srow;
      int gs = sslot ^ (row & 7);
      GLOAD_LDS16(h + (size_t)(brow + row) * 128 + gs * 8,
                  &h_lds[row * 128 + sslot * 8]);
    }
  }
  // ---- stage rw transposed as bf16: rw_lds[n][t_local] ----
  {
    int n = tid >> 3, t0 = (tid & 7) * 16;
#pragma unroll
    for (int i = 0; i < 16; ++i)
      rw_lds[n * BM + t0 + i] = f2bf(rw[(size_t)(brow + t0 + i) * 32 + n]);
  }
  __syncthreads();

  // ---- hoist all A-frags (same h cols for every expert) ----
  const int kg = lane >> 4;
  bf16x8 af[4][4];
#pragma unroll
  for (int m = 0; m < 4; ++m) {
    int row = wy * 64 + m * 16 + (lane & 15);
#pragma unroll
    for (int s = 0; s < 4; ++s) {
      int slot = s * 4 + kg;
      af[m][s] = *(const bf16x8*)&h_lds[row * 128 + ((slot ^ (row & 7)) * 8)];
    }
  }

  f32x4 acc[4][2] = {};
  const int srow = tid >> 4, sslot = tid & 15;

  for (int n = 0; n < 32; ++n) {
    // stage B tile for expert n: 64 rows(d) x 128 cols(r)
#pragma unroll
    for (int i = 0; i < 4; ++i) {
      int drow = i * 16 + srow;
      int gs = sslot ^ (drow & 7);
      GLOAD_LDS16(rkt + (size_t)(bcol + drow) * 4096 + n * 128 + gs * 8,
                  &Bs[drow * 128 + sslot * 8]);
    }
    __syncthreads();

    f32x4 accn[4][2] = {};
#pragma unroll
    for (int s = 0; s < 4; ++s) {
      int slot = s * 4 + kg;
      bf16x8 bfr[2];
#pragma unroll
      for (int j = 0; j < 2; ++j) {
        int drow = wx * 32 + j * 16 + (lane & 15);
        bfr[j] = *(const bf16x8*)&Bs[drow * 128 + ((slot ^ (drow & 7)) * 8)];
      }
#pragma unroll
      for (int m = 0; m < 4; ++m)
#pragma unroll
        for (int j = 0; j < 2; ++j)
          accn[m][j] = __builtin_amdgcn_mfma_f32_16x16x32_bf16(
              af[m][s], bfr[j], accn[m][j], 0, 0, 0);
    }

    // fold: acc += rw[t,n] * accn   (row scaling on C/D rows)
#pragma unroll
    for (int m = 0; m < 4; ++m) {
      int r0 = wy * 64 + m * 16 + (lane >> 4) * 4;
      ushort4 wv4 = *(const ushort4*)&rw_lds[n * BM + r0];
      float w0 = bf2f(wv4.x), w1 = bf2f(wv4.y), w2 = bf2f(wv4.z), w3 = bf2f(wv4.w);
#pragma unroll
      for (int j = 0; j < 2; ++j) {
        acc[m][j][0] += w0 * accn[m][j][0];
        acc[m][j][1] += w1 * accn[m][j][1];
        acc[m][j][2] += w2 * accn[m][j][2];
        acc[m][j][3] += w3 * accn[m][j][3];
      }
    }
    __syncthreads();   // all waves done with Bs before next stage
  }

  // ---- epilogue: f32 out ----
#pragma unroll
  for (int m = 0; m < 4; ++m) {
    int r0 = brow + wy * 64 + m * 16 + ((lane >> 4) * 4);
#pragma unroll
    for (int j = 0; j < 2; ++j) {
      int c = bcol + wx * 32 + j * 16 + (lane & 15);
#pragma unroll
      for (int q = 0; q < 4; ++q)
        out[(size_t)(r0 + q) * 1024 + c] = acc[m][j][q];
    }
  }
}

extern "C" void kernel_launch(void* const* d_in, const int* in_sizes, int n_in,
                              void* d_out, int out_size, void* d_ws, size_t ws_size,
                              hipStream_t stream) {
  const float* x  = (const float*)d_in[0];
  const float* fw = (const float*)d_in[1];
  const float* rw = (const float*)d_in[2];
  const float* fk = (const float*)d_in[3];
  const float* rk = (const float*)d_in[4];
  float* out = (float*)d_out;

  char* ws = (char*)d_ws;
  unsigned short* xb    = (unsigned short*)(ws);                // 8 MB (4096x1024)
  unsigned short* fkt   = (unsigned short*)(ws + (8u  << 20));  // 8 MB (4096x1024); reused as h after GEMM1
  unsigned short* rkt   = (unsigned short*)(ws + (16u << 20));  // 8 MB (1024x4096)
  unsigned short* allhw = (unsigned short*)(ws + (24u << 20));  // 32 MB (4096x4096)
  unsigned short* hbuf  = fkt;                                  // (4096x128) bf16, aliases fkt (dead after GEMM1)

  // 1) cast x -> bf16
  cast_f32_bf16<<<4096, 256, 0, stream>>>((const float4*)x, (ushort4*)xb, 1048576);
  // 2) fk (32,1024,128) -> FKT (4096 x 1024)
  transpose_cast<<<1024, 256, 0, stream>>>(fk, fkt, 1024, 128, 32, 2);
  // 3) rk (4096,1024) -> RKT (1024 x 4096)
  transpose_cast<<<1024, 256, 0, stream>>>(rk, rkt, 4096, 1024, 1024, 16);
  // 4) GEMM1: ALLHW = fw .* (xb @ FKT^T), bf16
  gemm_bt<128, 128><<<dim3(32, 32), 256, 0, stream>>>(xb, fkt, fw, allhw,
                                                      4096, 4096, 1024);
  // 5) reduce over experts -> h (overwrites fkt buffer; fkt dead now)
  reduce_h<<<256, 256, 0, stream>>>(allhw, hbuf);
  // 6) GEMM2 fused: out = sum_n diag(rw_n) * (h @ rk[n])
  gemm2_fused<<<dim3(16, 32), 256, 0, stream>>>(hbuf, rkt, rw, out);
}

// Round 3
// 98.250 us; speedup vs baseline: 1.3139x; 1.0669x over previous
//
#include <hip/hip_runtime.h>
#include <hip/hip_bf16.h>
#include <stdint.h>

// B=4, S=1024, D=1024, N=32, R=128; T = B*S = 4096.
// Pipeline:
//   xb    = bf16(x)                       (T x D)
//   FKT   = bf16(fk) transposed           (N*R x D)
//   RKT   = bf16(rk) transposed           (D x N*R)
//   ALLHW[t, n*128+r] = fw[t,n] * (xb @ FKT^T)   bf16  (GEMM1, fw in epilogue)
//   h[t,r] = sum_n ALLHW[t, n*128+r]             bf16  (reduce)
//   out = sum_n diag(rw[:,n]) * (h @ rk[n])      f32   (gemm2_fused)
// gemm2_fused: h staged once -> af hoisted to regs -> h's LDS reused as
// double-buffered Bs (forces af residency + 40KB LDS -> 3 blocks/CU).

typedef __attribute__((ext_vector_type(8))) short bf16x8;
typedef __attribute__((ext_vector_type(4))) float f32x4;

#define GLOAD_LDS16(gp, lp) __builtin_amdgcn_global_load_lds( \
    (const __attribute__((address_space(1))) void*)(gp), \
    (__attribute__((address_space(3))) void*)(lp), 16, 0, 0)

__device__ __forceinline__ unsigned short f2bf(float f) {
  uint32_t u = __float_as_uint(f);
  u += 0x7FFFu + ((u >> 16) & 1u);   // RNE
  return (unsigned short)(u >> 16);
}
__device__ __forceinline__ float bf2f(unsigned short b) {
  return __uint_as_float(((uint32_t)b) << 16);
}

// ---------------- prep: cast x to bf16 ----------------
__global__ void cast_f32_bf16(const float4* __restrict__ in,
                              ushort4* __restrict__ out, int n4) {
  int i = blockIdx.x * blockDim.x + threadIdx.x;
  if (i < n4) {
    float4 v = in[i];
    ushort4 o;
    o.x = f2bf(v.x); o.y = f2bf(v.y); o.z = f2bf(v.z); o.w = f2bf(v.w);
    out[i] = o;
  }
}

// ---------------- prep: batched transpose + cast -------------------
__global__ void transpose_cast(const float* __restrict__ in,
                               unsigned short* __restrict__ out,
                               int ROWS, int COLS, int tiles_per_batch, int ctiles) {
  __shared__ unsigned short tile[64][65];
  int bid = blockIdx.x;
  int b  = bid / tiles_per_batch;
  int tt = bid % tiles_per_batch;
  int rt = tt / ctiles, ct = tt % ctiles;
  const float* inb = in + (size_t)b * ROWS * COLS;
  unsigned short* outb = out + (size_t)b * ROWS * COLS;
  int lr = threadIdx.x >> 6;
  int lc = threadIdx.x & 63;
  int r0 = rt * 64, c0 = ct * 64;
#pragma unroll
  for (int i = 0; i < 16; ++i) {
    int r = lr * 16 + i;
    tile[r][lc] = f2bf(inb[(size_t)(r0 + r) * COLS + c0 + lc]);
  }
  __syncthreads();
#pragma unroll
  for (int i = 0; i < 16; ++i) {
    int c = lr * 16 + i;
    outb[(size_t)(c0 + c) * ROWS + r0 + lc] = tile[lc][c];
  }
}

// ---------------- reduce: h[t,r] = sum_n ALLHW[t, n*128+r] ----------
__global__ void reduce_h(const unsigned short* __restrict__ allhw,
                         unsigned short* __restrict__ h) {
  int tid = threadIdx.x;
  int t = blockIdx.x * 16 + (tid >> 4);
  int r8 = tid & 15;
  const unsigned short* p = allhw + (size_t)t * 4096 + r8 * 8;
  float acc[8] = {0,0,0,0,0,0,0,0};
#pragma unroll
  for (int n = 0; n < 32; ++n) {
    bf16x8 v = *(const bf16x8*)(p + n * 128);
#pragma unroll
    for (int j = 0; j < 8; ++j) acc[j] += bf2f((unsigned short)v[j]);
  }
  bf16x8 o;
#pragma unroll
  for (int j = 0; j < 8; ++j) o[j] = (short)f2bf(acc[j]);
  *(bf16x8*)(h + (size_t)t * 128 + r8 * 8) = o;
}

// ---------------- GEMM1: C = fw-weighted (A @ BT^T) -----------------
template <int BM, int BN>
__global__ __launch_bounds__(256, 2) void gemm_bt(
    const unsigned short* __restrict__ A,
    const unsigned short* __restrict__ BT,
    const float* __restrict__ fw,
    unsigned short* __restrict__ Cout, int M, int N, int K) {
  constexpr int BK = 64;
  constexpr int MREP = BM / 32;
  constexpr int NREP = BN / 32;
  __shared__ __align__(16) unsigned short As[BM * BK];
  __shared__ __align__(16) unsigned short Bs[BN * BK];

  const int tid = threadIdx.x;
  const int lane = tid & 63, wid = tid >> 6;
  const int wy = wid >> 1, wx = wid & 1;
  const int brow = blockIdx.y * BM;
  const int bcol = blockIdx.x * BN;
  const int nexp = blockIdx.x;              // expert id (BN==128==R)

  f32x4 acc[MREP][NREP] = {};

  const int srow = tid >> 3;
  const int sslot = tid & 7;

  for (int k0 = 0; k0 < K; k0 += BK) {
#pragma unroll
    for (int i = 0; i < BM / 32; ++i) {
      int row = i * 32 + srow;
      int gslot = sslot ^ (row & 7);
      GLOAD_LDS16(A + (size_t)(brow + row) * K + k0 + gslot * 8,
                  &As[row * BK + sslot * 8]);
    }
#pragma unroll
    for (int i = 0; i < BN / 32; ++i) {
      int row = i * 32 + srow;
      int gslot = sslot ^ (row & 7);
      GLOAD_LDS16(BT + (size_t)(bcol + row) * K + k0 + gslot * 8,
                  &Bs[row * BK + sslot * 8]);
    }
    __syncthreads();

#pragma unroll
    for (int ks = 0; ks < 2; ++ks) {
      const int kg = lane >> 4;
      const int slot = ks * 4 + kg;
      bf16x8 af[MREP], bfr[NREP];
#pragma unroll
      for (int m = 0; m < MREP; ++m) {
        int row = wy * (BM / 2) + m * 16 + (lane & 15);
        af[m] = *(const bf16x8*)&As[row * BK + ((slot ^ (row & 7)) * 8)];
      }
#pragma unroll
      for (int n = 0; n < NREP; ++n) {
        int row = wx * (BN / 2) + n * 16 + (lane & 15);
        bfr[n] = *(const bf16x8*)&Bs[row * BK + ((slot ^ (row & 7)) * 8)];
      }
#pragma unroll
      for (int m = 0; m < MREP; ++m)
#pragma unroll
        for (int n = 0; n < NREP; ++n)
          acc[m][n] = __builtin_amdgcn_mfma_f32_16x16x32_bf16(
              af[m], bfr[n], acc[m][n], 0, 0, 0);
    }
    __syncthreads();
  }

  const int crow0 = brow + wy * (BM / 2);
  const int ccol0 = bcol + wx * (BN / 2);
#pragma unroll
  for (int m = 0; m < MREP; ++m) {
    int r0 = crow0 + m * 16 + ((lane >> 4) * 4);
    float fwv[4];
#pragma unroll
    for (int j = 0; j < 4; ++j) fwv[j] = fw[(size_t)(r0 + j) * 32 + nexp];
#pragma unroll
    for (int n = 0; n < NREP; ++n) {
      int c = ccol0 + n * 16 + (lane & 15);
#pragma unroll
      for (int j = 0; j < 4; ++j)
        Cout[(size_t)(r0 + j) * N + c] = f2bf(fwv[j] * acc[m][n][j]);
    }
  }
}

// ---------------- GEMM2 fused: out = sum_n diag(rw_n)*(h @ rk[n]) ----
// h: (4096,128) bf16. rkt: (1024, 4096) bf16 [d][n*128+r]. rw: (4096,32) f32.
// out: (4096,1024) f32. BM=128 (t), BN=64 (d). grid (16, 32), 256 thr.
// LDS pool (32KB): holds h tile during hoist, then 2x16KB Bs double-buffer.
__global__ __launch_bounds__(256, 3) void gemm2_fused(
    const unsigned short* __restrict__ h,
    const unsigned short* __restrict__ rkt,
    const float* __restrict__ rw,
    float* __restrict__ out) {
  constexpr int BM = 128, BN = 64;
  __shared__ __align__(16) unsigned short pool[BM * 128];      // 32 KB
  __shared__ __align__(16) unsigned short rw_lds[32 * BM];     // 8 KB

  const int tid = threadIdx.x;
  const int lane = tid & 63, wid = tid >> 6;
  const int wy = wid >> 1, wx = wid & 1;
  const int brow = blockIdx.y * BM;   // token rows
  const int bcol = blockIdx.x * BN;   // d cols

  // ---- stage h block (once): 128 x 128, swizzled source ----
  {
    int srow = tid >> 4, sslot = tid & 15;
#pragma unroll
    for (int i = 0; i < 8; ++i) {
      int row = i * 16 + srow;
      int gs = sslot ^ (row & 7);
      GLOAD_LDS16(h + (size_t)(brow + row) * 128 + gs * 8,
                  &pool[row * 128 + sslot * 8]);
    }
  }
  // ---- stage rw transposed as bf16: rw_lds[n][t_local] ----
  // coalesced reads (thread = row-half), conflict-free strided writes.
  {
    int t = tid >> 1, half = tid & 1;
    const float* rp = rw + (size_t)(brow + t) * 32 + half * 16;
    float4 v0 = *(const float4*)(rp + 0);
    float4 v1 = *(const float4*)(rp + 4);
    float4 v2 = *(const float4*)(rp + 8);
    float4 v3 = *(const float4*)(rp + 12);
    float vals[16] = {v0.x, v0.y, v0.z, v0.w, v1.x, v1.y, v1.z, v1.w,
                      v2.x, v2.y, v2.z, v2.w, v3.x, v3.y, v3.z, v3.w};
#pragma unroll
    for (int i = 0; i < 16; ++i)
      rw_lds[(half * 16 + i) * BM + t] = f2bf(vals[i]);
  }
  __syncthreads();

  // ---- hoist all A-frags to registers (h about to be overwritten) ----
  const int kg = lane >> 4;
  bf16x8 af[4][4];
#pragma unroll
  for (int m = 0; m < 4; ++m) {
    int row = wy * 64 + m * 16 + (lane & 15);
#pragma unroll
    for (int s = 0; s < 4; ++s) {
      int slot = s * 4 + kg;
      af[m][s] = *(const bf16x8*)&pool[row * 128 + ((slot ^ (row & 7)) * 8)];
    }
  }
  __syncthreads();   // every wave done reading h before pool reuse

  unsigned short* Bs0 = pool;
  unsigned short* Bs1 = pool + 64 * 128;
  const int srow = tid >> 4, sslot = tid & 15;

  f32x4 acc[4][2] = {};

  // prologue: stage expert 0 into Bs0
#pragma unroll
  for (int i = 0; i < 4; ++i) {
    int drow = i * 16 + srow;
    int gs = sslot ^ (drow & 7);
    GLOAD_LDS16(rkt + (size_t)(bcol + drow) * 4096 + 0 * 128 + gs * 8,
                &Bs0[drow * 128 + sslot * 8]);
  }
  __syncthreads();

  for (int n = 0; n < 32; ++n) {
    const unsigned short* cur = (n & 1) ? Bs1 : Bs0;
    unsigned short* nxt = (n & 1) ? Bs0 : Bs1;
    if (n < 31) {   // issue next-expert stage early; lands during compute
#pragma unroll
      for (int i = 0; i < 4; ++i) {
        int drow = i * 16 + srow;
        int gs = sslot ^ (drow & 7);
        GLOAD_LDS16(rkt + (size_t)(bcol + drow) * 4096 + (n + 1) * 128 + gs * 8,
                    &nxt[drow * 128 + sslot * 8]);
      }
    }

    f32x4 accn[4][2] = {};
#pragma unroll
    for (int s = 0; s < 4; ++s) {
      int slot = s * 4 + kg;
      bf16x8 bfr[2];
#pragma unroll
      for (int j = 0; j < 2; ++j) {
        int drow = wx * 32 + j * 16 + (lane & 15);
        bfr[j] = *(const bf16x8*)&cur[drow * 128 + ((slot ^ (drow & 7)) * 8)];
      }
#pragma unroll
      for (int m = 0; m < 4; ++m)
#pragma unroll
        for (int j = 0; j < 2; ++j)
          accn[m][j] = __builtin_amdgcn_mfma_f32_16x16x32_bf16(
              af[m][s], bfr[j], accn[m][j], 0, 0, 0);
    }

    // fold: acc += rw[t,n] * accn
#pragma unroll
    for (int m = 0; m < 4; ++m) {
      int r0 = wy * 64 + m * 16 + (lane >> 4) * 4;
      ushort4 wv4 = *(const ushort4*)&rw_lds[n * BM + r0];
      float w0 = bf2f(wv4.x), w1 = bf2f(wv4.y), w2 = bf2f(wv4.z), w3 = bf2f(wv4.w);
#pragma unroll
      for (int j = 0; j < 2; ++j) {
        acc[m][j][0] += w0 * accn[m][j][0];
        acc[m][j][1] += w1 * accn[m][j][1];
        acc[m][j][2] += w2 * accn[m][j][2];
        acc[m][j][3] += w3 * accn[m][j][3];
      }
    }
    __syncthreads();   // next buffer staged + all waves done with cur
  }

  // ---- epilogue: f32 out ----
#pragma unroll
  for (int m = 0; m < 4; ++m) {
    int r0 = brow + wy * 64 + m * 16 + ((lane >> 4) * 4);
#pragma unroll
    for (int j = 0; j < 2; ++j) {
      int c = bcol + wx * 32 + j * 16 + (lane & 15);
#pragma unroll
      for (int q = 0; q < 4; ++q)
        out[(size_t)(r0 + q) * 1024 + c] = acc[m][j][q];
    }
  }
}

extern "C" void kernel_launch(void* const* d_in, const int* in_sizes, int n_in,
                              void* d_out, int out_size, void* d_ws, size_t ws_size,
                              hipStream_t stream) {
  const float* x  = (const float*)d_in[0];
  const float* fw = (const float*)d_in[1];
  const float* rw = (const float*)d_in[2];
  const float* fk = (const float*)d_in[3];
  const float* rk = (const float*)d_in[4];
  float* out = (float*)d_out;

  char* ws = (char*)d_ws;
  unsigned short* xb    = (unsigned short*)(ws);                // 8 MB (4096x1024)
  unsigned short* fkt   = (unsigned short*)(ws + (8u  << 20));  // 8 MB; reused as h after GEMM1
  unsigned short* rkt   = (unsigned short*)(ws + (16u << 20));  // 8 MB (1024x4096)
  unsigned short* allhw = (unsigned short*)(ws + (24u << 20));  // 32 MB (4096x4096)
  unsigned short* hbuf  = fkt;                                  // (4096x128) bf16

  cast_f32_bf16<<<4096, 256, 0, stream>>>((const float4*)x, (ushort4*)xb, 1048576);
  transpose_cast<<<1024, 256, 0, stream>>>(fk, fkt, 1024, 128, 32, 2);
  transpose_cast<<<1024, 256, 0, stream>>>(rk, rkt, 4096, 1024, 1024, 16);
  gemm_bt<128, 128><<<dim3(32, 32), 256, 0, stream>>>(xb, fkt, fw, allhw,
                                                      4096, 4096, 1024);
  reduce_h<<<256, 256, 0, stream>>>(allhw, hbuf);
  gemm2_fused<<<dim3(16, 32), 256, 0, stream>>>(hbuf, rkt, rw, out);
}

// Round 4
// 95.518 us; speedup vs baseline: 1.3515x; 1.0286x over previous
//
#include <hip/hip_runtime.h>
#include <hip/hip_bf16.h>
#include <stdint.h>

// B=4, S=1024, D=1024, N=32, R=128; T = B*S = 4096.
// Pipeline:
//   xb    = bf16(x)                       (T x D)
//   FKT   = bf16(fk) transposed           (N*R x D)
//   RKT   = bf16(rk) transposed           (D x N*R)
//   ALLHW[t, n*128+r] = fw[t,n] * (xb @ FKT^T)   bf16  (GEMM1: 256^2 8-phase)
//   h[t,r] = sum_n ALLHW[t, n*128+r]             bf16  (reduce)
//   out = sum_n diag(rw[:,n]) * (h @ rk[n])      f32   (gemm2_fused)

typedef __attribute__((ext_vector_type(8))) short bf16x8;
typedef __attribute__((ext_vector_type(4))) float f32x4;

#define GLOAD_LDS16(gp, lp) __builtin_amdgcn_global_load_lds( \
    (const __attribute__((address_space(1))) void*)(gp), \
    (__attribute__((address_space(3))) void*)(lp), 16, 0, 0)

__device__ __forceinline__ unsigned short f2bf(float f) {
  uint32_t u = __float_as_uint(f);
  u += 0x7FFFu + ((u >> 16) & 1u);   // RNE
  return (unsigned short)(u >> 16);
}
__device__ __forceinline__ float bf2f(unsigned short b) {
  return __uint_as_float(((uint32_t)b) << 16);
}

// ---------------- prep: cast x to bf16 ----------------
__global__ void cast_f32_bf16(const float4* __restrict__ in,
                              ushort4* __restrict__ out, int n4) {
  int i = blockIdx.x * blockDim.x + threadIdx.x;
  if (i < n4) {
    float4 v = in[i];
    ushort4 o;
    o.x = f2bf(v.x); o.y = f2bf(v.y); o.z = f2bf(v.z); o.w = f2bf(v.w);
    out[i] = o;
  }
}

// ---------------- prep: batched transpose + cast -------------------
__global__ void transpose_cast(const float* __restrict__ in,
                               unsigned short* __restrict__ out,
                               int ROWS, int COLS, int tiles_per_batch, int ctiles) {
  __shared__ unsigned short tile[64][65];
  int bid = blockIdx.x;
  int b  = bid / tiles_per_batch;
  int tt = bid % tiles_per_batch;
  int rt = tt / ctiles, ct = tt % ctiles;
  const float* inb = in + (size_t)b * ROWS * COLS;
  unsigned short* outb = out + (size_t)b * ROWS * COLS;
  int lr = threadIdx.x >> 6;
  int lc = threadIdx.x & 63;
  int r0 = rt * 64, c0 = ct * 64;
#pragma unroll
  for (int i = 0; i < 16; ++i) {
    int r = lr * 16 + i;
    tile[r][lc] = f2bf(inb[(size_t)(r0 + r) * COLS + c0 + lc]);
  }
  __syncthreads();
#pragma unroll
  for (int i = 0; i < 16; ++i) {
    int c = lr * 16 + i;
    outb[(size_t)(c0 + c) * ROWS + r0 + lc] = tile[lc][c];
  }
}

// ---------------- reduce: h[t,r] = sum_n ALLHW[t, n*128+r] ----------
__global__ void reduce_h(const unsigned short* __restrict__ allhw,
                         unsigned short* __restrict__ h) {
  int tid = threadIdx.x;
  int t = blockIdx.x * 16 + (tid >> 4);
  int r8 = tid & 15;
  const unsigned short* p = allhw + (size_t)t * 4096 + r8 * 8;
  float acc[8] = {0,0,0,0,0,0,0,0};
#pragma unroll
  for (int n = 0; n < 32; ++n) {
    bf16x8 v = *(const bf16x8*)(p + n * 128);
#pragma unroll
    for (int j = 0; j < 8; ++j) acc[j] += bf2f((unsigned short)v[j]);
  }
  bf16x8 o;
#pragma unroll
  for (int j = 0; j < 8; ++j) o[j] = (short)f2bf(acc[j]);
  *(bf16x8*)(h + (size_t)t * 128 + r8 * 8) = o;
}

// ---------------- GEMM1: 256x256 tile, 8-phase counted-vmcnt --------
// A: xb (4096x1024) bf16. Bt: FKT (4096x1024) bf16. C: allhw (4096x4096) bf16.
// 512 thr = 8 waves (2M x 4N); BK=64; 16 K-tiles, 2 per iteration.
// LDS 128 KB: lds[buf][A/B][half][128x64]. Even tiles->buf0, odd->buf1.
// Per phase: ds-read frag subtile | 1 half-tile gload_lds prefetch |
// barrier | lgkmcnt(0)+sched_barrier | setprio(1) 16xMFMA setprio(0) | barrier.
// vmcnt(4) at phases 4 & 8 (tile-complete); slot lifetimes verified:
// B-halves free after ph2/ph6, A-halves after ph3/ph7.
__global__ __launch_bounds__(512, 2) void gemm1_8ph(
    const unsigned short* __restrict__ A,
    const unsigned short* __restrict__ Bt,
    const float* __restrict__ fw,
    unsigned short* __restrict__ Cout) {
  __shared__ __align__(16) unsigned short lds[2][2][2][8192];  // 128 KB

  const int tid = threadIdx.x;
  const int lane = tid & 63, wid = tid >> 6;
  const int wy = wid >> 2;        // 0..1  (M)
  const int wx = wid & 3;         // 0..3  (N)
  const int lrow = lane & 15;
  const int kg = lane >> 4;
  const int bhalf = wx >> 1;      // which B half-tile this wave reads
  const int brow_b = (wx & 1) * 64;

  // XCD-aware swizzle (256 wgs, 256 % 8 == 0 -> simple form is bijective)
  const int wg = blockIdx.x;
  const int swz = (wg & 7) * 32 + (wg >> 3);
  const int brow = (swz >> 4) * 256;
  const int bcol = (swz & 15) * 256;

  f32x4 acc[8][4] = {};
  bf16x8 aF[4][2], bF0[2][2], bF1[2][2];

#define STAGE(buf, ab, half, G, g0, kcol) do { \
  _Pragma("unroll") for (int j_ = 0; j_ < 2; ++j_) { \
    int row_ = (tid >> 3) + j_ * 64; \
    int slot_ = tid & 7; \
    GLOAD_LDS16((G) + (size_t)((g0) + row_) * 1024 + (kcol) + ((slot_ ^ (row_ & 7)) * 8), \
                &lds[buf][ab][half][row_ * 64 + slot_ * 8]); \
  } } while (0)

#define DS_A(buf, mi) do { \
  const unsigned short* base_ = &lds[buf][0][wy][0]; \
  _Pragma("unroll") for (int m_ = 0; m_ < 4; ++m_) { \
    int row_ = (mi) * 64 + m_ * 16 + lrow; \
    _Pragma("unroll") for (int ks_ = 0; ks_ < 2; ++ks_) \
      aF[m_][ks_] = *(const bf16x8*)&base_[row_ * 64 + (((ks_ * 4 + kg) ^ (row_ & 7)) * 8)]; \
  } } while (0)

#define DS_B(buf, ni, BF) do { \
  const unsigned short* base_ = &lds[buf][1][bhalf][0]; \
  _Pragma("unroll") for (int nf_ = 0; nf_ < 2; ++nf_) { \
    int row_ = brow_b + (ni) * 32 + nf_ * 16 + lrow; \
    _Pragma("unroll") for (int ks_ = 0; ks_ < 2; ++ks_) \
      BF[nf_][ks_] = *(const bf16x8*)&base_[row_ * 64 + (((ks_ * 4 + kg) ^ (row_ & 7)) * 8)]; \
  } } while (0)

#define MFMA16(mi, ni, BF) do { \
  __builtin_amdgcn_s_setprio(1); \
  _Pragma("unroll") for (int ks_ = 0; ks_ < 2; ++ks_) \
  _Pragma("unroll") for (int m_ = 0; m_ < 4; ++m_) \
  _Pragma("unroll") for (int nf_ = 0; nf_ < 2; ++nf_) \
    acc[(mi) * 4 + m_][(ni) * 2 + nf_] = __builtin_amdgcn_mfma_f32_16x16x32_bf16( \
        aF[m_][ks_], BF[nf_][ks_], acc[(mi) * 4 + m_][(ni) * 2 + nf_], 0, 0, 0); \
  __builtin_amdgcn_s_setprio(0); \
  } while (0)

#define BAR() __builtin_amdgcn_s_barrier()
#define LGKM0() do { asm volatile("s_waitcnt lgkmcnt(0)" ::: "memory"); \
                     __builtin_amdgcn_sched_barrier(0); } while (0)
#define VMW(n) asm volatile("s_waitcnt vmcnt(" #n ")" ::: "memory")

  // ---- prologue: tile0 (buf0) fully + B halves of tile1 (buf1) ----
  STAGE(0, 0, 0, A,  brow,        0);
  STAGE(0, 0, 1, A,  brow + 128,  0);
  STAGE(0, 1, 0, Bt, bcol,        0);
  STAGE(0, 1, 1, Bt, bcol + 128,  0);
  STAGE(1, 1, 0, Bt, bcol,        64);
  STAGE(1, 1, 1, Bt, bcol + 128,  64);
  VMW(4);                        // tile 0 landed; B0(1),B1(1) in flight
  BAR();

#pragma unroll 1
  for (int i = 0; i < 8; ++i) {
    const int k1 = (2 * i + 1) * 64;   // tile t+1 k-offset
    const int k2 = (2 * i + 2) * 64;   // tile t+2
    const int k3 = (2 * i + 3) * 64;   // tile t+3
    // ---- phase 1: quad(0,0) of tile t (buf0); prefetch A0(t+1)->buf1 ----
    DS_A(0, 0); DS_B(0, 0, bF0);
    STAGE(1, 0, 0, A, brow, k1);
    BAR(); LGKM0();
    MFMA16(0, 0, bF0);
    BAR();
    // ---- phase 2: quad(0,1); prefetch A1(t+1) ----
    DS_B(0, 1, bF1);
    STAGE(1, 0, 1, A, brow + 128, k1);
    BAR(); LGKM0();
    MFMA16(0, 1, bF1);
    BAR();
    // ---- phase 3: quad(1,0); prefetch B0(t+2)->buf0 (freed after ph2) ----
    DS_A(0, 1);
    if (i < 7) STAGE(0, 1, 0, Bt, bcol, k2);
    BAR(); LGKM0();
    MFMA16(1, 0, bF0);
    BAR();
    // ---- phase 4: quad(1,1); prefetch B1(t+2); tile t+1 must land ----
    if (i < 7) { STAGE(0, 1, 1, Bt, bcol + 128, k2); VMW(4); }
    else       { VMW(0); }
    BAR();
    MFMA16(1, 1, bF1);
    BAR();
    // ---- phase 5: quad(0,0) of tile t+1 (buf1); prefetch A0(t+2) (freed ph3) ----
    DS_A(1, 0); DS_B(1, 0, bF0);
    if (i < 7) STAGE(0, 0, 0, A, brow, k2);
    BAR(); LGKM0();
    MFMA16(0, 0, bF0);
    BAR();
    // ---- phase 6: quad(0,1); prefetch A1(t+2) ----
    DS_B(1, 1, bF1);
    if (i < 7) STAGE(0, 0, 1, A, brow + 128, k2);
    BAR(); LGKM0();
    MFMA16(0, 1, bF1);
    BAR();
    // ---- phase 7: quad(1,0); prefetch B0(t+3)->buf1 (freed after ph6) ----
    DS_A(1, 1);
    if (i < 7) STAGE(1, 1, 0, Bt, bcol, k3);
    BAR(); LGKM0();
    MFMA16(1, 0, bF0);
    BAR();
    // ---- phase 8: quad(1,1); prefetch B1(t+3); tile t+2 must land ----
    if (i < 7) { STAGE(1, 1, 1, Bt, bcol + 128, k3); VMW(4); }
    BAR();
    MFMA16(1, 1, bF1);
    BAR();
  }
#undef STAGE
#undef DS_A
#undef DS_B
#undef MFMA16
#undef BAR
#undef LGKM0
#undef VMW

  // ---- epilogue: fw-weighted bf16 store ----
  const int lr4 = (lane >> 4) * 4;
  const int ebase = bcol >> 7;
#pragma unroll
  for (int m = 0; m < 8; ++m) {
    int r0 = brow + wy * 128 + m * 16 + lr4;
    float fwv[4][2];
#pragma unroll
    for (int q = 0; q < 4; ++q) {
      fwv[q][0] = fw[(size_t)(r0 + q) * 32 + ebase + ((wx * 64) >> 7)];
      fwv[q][1] = fw[(size_t)(r0 + q) * 32 + ebase + ((wx * 64 + 48) >> 7)];
    }
#pragma unroll
    for (int nf = 0; nf < 4; ++nf) {
      int el = (wx * 64 + nf * 16) >> 7;        // 0 or 1 within this wave
      int eidx = ((wx * 64 + nf * 16) >> 7) == ((wx * 64) >> 7) ? 0 : 1;
      int c = bcol + wx * 64 + nf * 16 + (lane & 15);
      (void)el;
#pragma unroll
      for (int q = 0; q < 4; ++q)
        Cout[(size_t)(r0 + q) * 4096 + c] = f2bf(fwv[q][eidx] * acc[m][nf][q]);
    }
  }
}

// ---------------- GEMM2 fused: out = sum_n diag(rw_n)*(h @ rk[n]) ----
__global__ __launch_bounds__(256, 3) void gemm2_fused(
    const unsigned short* __restrict__ h,
    const unsigned short* __restrict__ rkt,
    const float* __restrict__ rw,
    float* __restrict__ out) {
  constexpr int BM = 128, BN = 64;
  __shared__ __align__(16) unsigned short pool[BM * 128];      // 32 KB
  __shared__ __align__(16) unsigned short rw_lds[32 * BM];     // 8 KB

  const int tid = threadIdx.x;
  const int lane = tid & 63, wid = tid >> 6;
  const int wy = wid >> 1, wx = wid & 1;
  const int brow = blockIdx.y * BM;
  const int bcol = blockIdx.x * BN;

  {
    int srow = tid >> 4, sslot = tid & 15;
#pragma unroll
    for (int i = 0; i < 8; ++i) {
      int row = i * 16 + srow;
      int gs = sslot ^ (row & 7);
      GLOAD_LDS16(h + (size_t)(brow + row) * 128 + gs * 8,
                  &pool[row * 128 + sslot * 8]);
    }
  }
  {
    int t = tid >> 1, half = tid & 1;
    const float* rp = rw + (size_t)(brow + t) * 32 + half * 16;
    float4 v0 = *(const float4*)(rp + 0);
    float4 v1 = *(const float4*)(rp + 4);
    float4 v2 = *(const float4*)(rp + 8);
    float4 v3 = *(const float4*)(rp + 12);
    float vals[16] = {v0.x, v0.y, v0.z, v0.w, v1.x, v1.y, v1.z, v1.w,
                      v2.x, v2.y, v2.z, v2.w, v3.x, v3.y, v3.z, v3.w};
#pragma unroll
    for (int i = 0; i < 16; ++i)
      rw_lds[(half * 16 + i) * BM + t] = f2bf(vals[i]);
  }
  __syncthreads();

  const int kg = lane >> 4;
  bf16x8 af[4][4];
#pragma unroll
  for (int m = 0; m < 4; ++m) {
    int row = wy * 64 + m * 16 + (lane & 15);
#pragma unroll
    for (int s = 0; s < 4; ++s) {
      int slot = s * 4 + kg;
      af[m][s] = *(const bf16x8*)&pool[row * 128 + ((slot ^ (row & 7)) * 8)];
    }
  }
  __syncthreads();

  unsigned short* Bs0 = pool;
  unsigned short* Bs1 = pool + 64 * 128;
  const int srow = tid >> 4, sslot = tid & 15;

  f32x4 acc[4][2] = {};

#pragma unroll
  for (int i = 0; i < 4; ++i) {
    int drow = i * 16 + srow;
    int gs = sslot ^ (drow & 7);
    GLOAD_LDS16(rkt + (size_t)(bcol + drow) * 4096 + gs * 8,
                &Bs0[drow * 128 + sslot * 8]);
  }
  __syncthreads();

  for (int n = 0; n < 32; ++n) {
    const unsigned short* cur = (n & 1) ? Bs1 : Bs0;
    unsigned short* nxt = (n & 1) ? Bs0 : Bs1;
    if (n < 31) {
#pragma unroll
      for (int i = 0; i < 4; ++i) {
        int drow = i * 16 + srow;
        int gs = sslot ^ (drow & 7);
        GLOAD_LDS16(rkt + (size_t)(bcol + drow) * 4096 + (n + 1) * 128 + gs * 8,
                    &nxt[drow * 128 + sslot * 8]);
      }
    }

    f32x4 accn[4][2] = {};
#pragma unroll
    for (int s = 0; s < 4; ++s) {
      int slot = s * 4 + kg;
      bf16x8 bfr[2];
#pragma unroll
      for (int j = 0; j < 2; ++j) {
        int drow = wx * 32 + j * 16 + (lane & 15);
        bfr[j] = *(const bf16x8*)&cur[drow * 128 + ((slot ^ (drow & 7)) * 8)];
      }
#pragma unroll
      for (int m = 0; m < 4; ++m)
#pragma unroll
        for (int j = 0; j < 2; ++j)
          accn[m][j] = __builtin_amdgcn_mfma_f32_16x16x32_bf16(
              af[m][s], bfr[j], accn[m][j], 0, 0, 0);
    }

#pragma unroll
    for (int m = 0; m < 4; ++m) {
      int r0 = wy * 64 + m * 16 + (lane >> 4) * 4;
      ushort4 wv4 = *(const ushort4*)&rw_lds[n * BM + r0];
      float w0 = bf2f(wv4.x), w1 = bf2f(wv4.y), w2 = bf2f(wv4.z), w3 = bf2f(wv4.w);
#pragma unroll
      for (int j = 0; j < 2; ++j) {
        acc[m][j][0] += w0 * accn[m][j][0];
        acc[m][j][1] += w1 * accn[m][j][1];
        acc[m][j][2] += w2 * accn[m][j][2];
        acc[m][j][3] += w3 * accn[m][j][3];
      }
    }
    __syncthreads();
  }

#pragma unroll
  for (int m = 0; m < 4; ++m) {
    int r0 = brow + wy * 64 + m * 16 + ((lane >> 4) * 4);
#pragma unroll
    for (int j = 0; j < 2; ++j) {
      int c = bcol + wx * 32 + j * 16 + (lane & 15);
#pragma unroll
      for (int q = 0; q < 4; ++q)
        out[(size_t)(r0 + q) * 1024 + c] = acc[m][j][q];
    }
  }
}

extern "C" void kernel_launch(void* const* d_in, const int* in_sizes, int n_in,
                              void* d_out, int out_size, void* d_ws, size_t ws_size,
                              hipStream_t stream) {
  const float* x  = (const float*)d_in[0];
  const float* fw = (const float*)d_in[1];
  const float* rw = (const float*)d_in[2];
  const float* fk = (const float*)d_in[3];
  const float* rk = (const float*)d_in[4];
  float* out = (float*)d_out;

  char* ws = (char*)d_ws;
  unsigned short* xb    = (unsigned short*)(ws);                // 8 MB (4096x1024)
  unsigned short* fkt   = (unsigned short*)(ws + (8u  << 20));  // 8 MB; reused as h after GEMM1
  unsigned short* rkt   = (unsigned short*)(ws + (16u << 20));  // 8 MB (1024x4096)
  unsigned short* allhw = (unsigned short*)(ws + (24u << 20));  // 32 MB (4096x4096)
  unsigned short* hbuf  = fkt;                                  // (4096x128) bf16

  cast_f32_bf16<<<4096, 256, 0, stream>>>((const float4*)x, (ushort4*)xb, 1048576);
  transpose_cast<<<1024, 256, 0, stream>>>(fk, fkt, 1024, 128, 32, 2);
  transpose_cast<<<1024, 256, 0, stream>>>(rk, rkt, 4096, 1024, 1024, 16);
  gemm1_8ph<<<256, 512, 0, stream>>>(xb, fkt, fw, allhw);
  reduce_h<<<256, 256, 0, stream>>>(allhw, hbuf);
  gemm2_fused<<<dim3(16, 32), 256, 0, stream>>>(hbuf, rkt, rw, out);
}